// Round 2
// baseline (76.283 us; speedup 1.0000x reference)
//
#include <hip/hip_runtime.h>

// ConvCapsules2d: V[b,i,c,d,f,g,k,l] = (sum_p poses[b,i,p,2f+k,2g+l]) * W[i,c,d,k,l]
// shapes: poses (16,32,16,14,14) f32, W (32,32,16,3,3) f32
// out (16,32,32,16,6,6,3,3) f32  = 84,934,656 elems = 339.7 MB  -> write-bound.

#define N_BATCH 16
#define B_IN    32
#define P_DIM   16
#define H_IN    14
#define C_OUT   32
#define D_OUT   16
#define KSZ     3
#define FSZ     6

typedef float f32x4 __attribute__((ext_vector_type(4)));

// per-(b,i): s tile = F*F*K*K = 6*6*3*3 = 324 floats (layout matches output inner dims)
#define S_ELEMS 324
// c-quad of 8: W slice = 8 * D_OUT * 9 = 1152 floats (contiguous in W)
#define CQ      8
#define W_ELEMS (CQ * D_OUT * KSZ * KSZ)   // 1152
// float4 stores per block: 8 c * 16 d * (324/4) = 10368
#define V4_PER_BLOCK (CQ * D_OUT * (S_ELEMS / 4))

__global__ __launch_bounds__(256)
void convcaps_kernel(const float* __restrict__ poses,
                     const float* __restrict__ W,
                     float* __restrict__ out)
{
    __shared__ float s_lds[S_ELEMS];
    __shared__ float w_lds[W_ELEMS];

    const int tid = threadIdx.x;
    const int blk = blockIdx.x;        // 0 .. 2047
    const int cq  = blk & 3;           // which c-quad (8 c's each)
    const int bi  = blk >> 2;          // 0 .. 511
    const int i   = bi & (B_IN - 1);
    const int b   = bi >> 5;
    const int c0  = cq * CQ;

    // ---- stage 1: s[e] = sum_p poses[b,i,p, 2f+k, 2g+l], e = ((f*6+g)*3+k)*3+l
    for (int e = tid; e < S_ELEMS; e += 256) {
        int f  = e / 54;               // 54 = 6*9
        int r  = e - f * 54;
        int g  = r / 9;
        int kl = r - g * 9;
        int k  = kl / 3;
        int l  = kl - k * 3;
        int h  = 2 * f + k;
        int w  = 2 * g + l;
        const float* p0 = poses
            + (size_t)(b * B_IN + i) * (P_DIM * H_IN * H_IN)
            + h * H_IN + w;
        float acc = 0.f;
        #pragma unroll
        for (int p = 0; p < P_DIM; ++p) acc += p0[p * (H_IN * H_IN)];
        s_lds[e] = acc;
    }

    // ---- stage 2: W[i, c0..c0+7, :, :, :] is a contiguous run of 1152 floats
    {
        const float* wsrc = W + (size_t)(i * C_OUT + c0) * (D_OUT * KSZ * KSZ);
        for (int j = tid; j < W_ELEMS; j += 256) w_lds[j] = wsrc[j];
    }
    __syncthreads();

    // ---- stage 3: write 8*16*324 floats, coalesced float4 nontemporal stores
    float* obase = out + (size_t)((b * B_IN + i) * C_OUT + c0) * (D_OUT * S_ELEMS);

    for (int idx = tid; idx < V4_PER_BLOCK; idx += 256) {
        int cd = idx / 81;             // (c_off*16 + d), 0..127
        int q  = idx - cd * 81;        // float4 slot within 324
        int e  = q * 4;

        const float* wrow = &w_lds[cd * 9];   // cd*9 == (c_off*144 + d*9)
        f32x4 v;
        {
            int kl0 = (e + 0) % 9;
            int kl1 = (e + 1) % 9;
            int kl2 = (e + 2) % 9;
            int kl3 = (e + 3) % 9;
            v.x = s_lds[e + 0] * wrow[kl0];
            v.y = s_lds[e + 1] * wrow[kl1];
            v.z = s_lds[e + 2] * wrow[kl2];
            v.w = s_lds[e + 3] * wrow[kl3];
        }
        // offsets: cd*324 floats = 1296 B (16B-multiple), e*4 B (16B-multiple),
        // obase is a multiple of D_OUT*324 floats -> all stores 16B aligned.
        __builtin_nontemporal_store(v, (f32x4*)(obase + (size_t)cd * S_ELEMS + e));
    }
}

extern "C" void kernel_launch(void* const* d_in, const int* in_sizes, int n_in,
                              void* d_out, int out_size, void* d_ws, size_t ws_size,
                              hipStream_t stream) {
    const float* poses = (const float*)d_in[0];
    const float* W     = (const float*)d_in[1];
    float* out         = (float*)d_out;

    const int grid = N_BATCH * B_IN * (C_OUT / CQ);   // 16*32*4 = 2048
    convcaps_kernel<<<grid, 256, 0, stream>>>(poses, W, out);
}